// Round 1
// baseline (1038.585 us; speedup 1.0000x reference)
//
#include <hip/hip_runtime.h>
#include <stdint.h>

#define B_N   16384
#define S_N   256
#define NCH   8
#define P_N   (B_N * S_N)      // 4194304 positions (b,s)
#define EPS_F 1e-5f

typedef float  f32x4  __attribute__((ext_vector_type(4)));
typedef __bf16 bf16x8 __attribute__((ext_vector_type(8)));
typedef unsigned int u32x4 __attribute__((ext_vector_type(4)));
typedef unsigned int u32x2 __attribute__((ext_vector_type(2)));

static __device__ __forceinline__ unsigned short f2bf(float f) {
  union { float f; unsigned u; } v; v.f = f;
  unsigned u = v.u;
  u += 0x7fffu + ((u >> 16) & 1u);          // RNE
  return (unsigned short)(u >> 16);
}
static __device__ __forceinline__ float bf2f(unsigned short h) {
  union { unsigned u; float f; } v; v.u = ((unsigned)h) << 16;
  return v.f;
}

// ---------------- pass 1: per-channel stats + planar bf16 transpose ----------------
// x (B,S,16) fp32 -> xplan[16][P_N] bf16 (raw, un-normalized), stats[32] = {sum[16], sumsq[16]}
#define TP 1024
__global__ __launch_bounds__(256) void pass1_kernel(
    const float* __restrict__ x, unsigned short* __restrict__ xplan,
    float* __restrict__ stats)
{
  __shared__ unsigned short sh[16][TP + 8];
  const int t = threadIdx.x;
  const size_t tp0 = (size_t)blockIdx.x * TP;
  const int c0 = (t & 3) * 4;               // each thread owns 4 fixed channels
  float s[4] = {0.f,0.f,0.f,0.f}, q[4] = {0.f,0.f,0.f,0.f};
  const f32x4* xv = (const f32x4*)x;
  #pragma unroll
  for (int i = 0; i < TP/64; ++i) {         // 16 coalesced float4 iterations
    size_t idx = tp0 * 4 + (size_t)i * 256 + t;
    f32x4 v = xv[idx];
    int ploc = (i * 256 + t) >> 2;
    #pragma unroll
    for (int j = 0; j < 4; ++j) {
      sh[c0 + j][ploc] = f2bf(v[j]);
      s[j] += v[j];
      q[j] += v[j] * v[j];
    }
  }
  #pragma unroll
  for (int off = 32; off >= 4; off >>= 1) {
    #pragma unroll
    for (int j = 0; j < 4; ++j) { s[j] += __shfl_down(s[j], off); q[j] += __shfl_down(q[j], off); }
  }
  const int lane = t & 63;
  if (lane < 4) {                           // lane L holds channels L*4..L*4+3
    #pragma unroll
    for (int j = 0; j < 4; ++j) {
      atomicAdd(&stats[lane * 4 + j], s[j]);
      atomicAdd(&stats[16 + lane * 4 + j], q[j]);
    }
  }
  __syncthreads();
  #pragma unroll
  for (int c = 0; c < 16; ++c) {            // coalesced 8B-per-thread plane writeout
    u32x2 v = *(const u32x2*)&sh[c][t * 4];
    *(u32x2*)(xplan + (size_t)c * P_N + tp0 + t * 4) = v;
  }
}

// ---------------- W prep: fp32 -> bf16 + rowsums ----------------
__global__ __launch_bounds__(256) void wprep_kernel(
    const float* __restrict__ Wr, const float* __restrict__ Wi,
    unsigned short* __restrict__ wr_bf, unsigned short* __restrict__ wi_bf,
    float* __restrict__ RWr, float* __restrict__ RWi)
{
  __shared__ float sr[4], si[4];
  const int row = blockIdx.x, t = threadIdx.x;   // row = c*256 + o
  const size_t idx = (size_t)row * 256 + t;
  float vr = Wr[idx], vi = Wi[idx];
  wr_bf[idx] = f2bf(vr);
  wi_bf[idx] = f2bf(vi);
  float rr = vr, ri = vi;
  #pragma unroll
  for (int off = 32; off >= 1; off >>= 1) { rr += __shfl_down(rr, off); ri += __shfl_down(ri, off); }
  if ((t & 63) == 0) { sr[t >> 6] = rr; si[t >> 6] = ri; }
  __syncthreads();
  if (t == 0) {
    RWr[row] = sr[0] + sr[1] + sr[2] + sr[3];
    RWi[row] = si[0] + si[1] + si[2] + si[3];
  }
}

// ---------------- stats finalize: A = g*rsqrt(var+eps), C = b - mu*A ----------------
__global__ void finalize_kernel(const float* __restrict__ stats,
                                const float* __restrict__ g_in, const float* __restrict__ b_in,
                                float* __restrict__ AC)
{
  int ch = threadIdx.x;
  if (ch < 16) {
    float n = (float)P_N;
    float mu  = stats[ch] / n;
    float var = stats[16 + ch] / n - mu * mu;
    float A = g_in[ch] * rsqrtf(var + EPS_F);
    AC[ch] = A;
    AC[16 + ch] = b_in[ch] - mu * A;
  }
}

// ---------------- K terms: Kr = Ci*RWr - Cq*RWi ; Ki = Cq*RWr + Ci*RWi ----------------
__global__ __launch_bounds__(256) void kterm_kernel(
    const float* __restrict__ AC, const float* __restrict__ RWr, const float* __restrict__ RWi,
    float* __restrict__ Kr, float* __restrict__ Ki)
{
  int idx = blockIdx.x * 256 + threadIdx.x;   // 2048 = c*256+o
  int c = idx >> 8;
  float Ci_ = AC[16 + 2*c], Cq_ = AC[16 + 2*c + 1];
  Kr[idx] = Ci_ * RWr[idx] - Cq_ * RWi[idx];
  Ki[idx] = Cq_ * RWr[idx] + Ci_ * RWi[idx];
}

// ---------------- main: per-channel complex MFMA matmul + amp2-weighted contraction ----------------
// block = 256 thr (4 waves), 32 batch rows; waves tile o; K-chunks of 32 staged in LDS.
__global__ __launch_bounds__(256, 2) void main_kernel(
    const unsigned short* __restrict__ xplan,
    const unsigned short* __restrict__ wr_bf,
    const unsigned short* __restrict__ wi_bf,
    const float* __restrict__ AC,
    const float* __restrict__ Kr, const float* __restrict__ Ki,
    const float* __restrict__ Wfr, const float* __restrict__ Wfi,
    float* __restrict__ y)
{
  __shared__ unsigned short Xi[32][264];   // +8 pad: row stride 528B -> banks spread
  __shared__ unsigned short Xq[32][264];
  __shared__ unsigned short Wrl[128][40];  // +8 pad: row stride 80B
  __shared__ unsigned short Wil[128][40];
  __shared__ float red[4][32][2];

  const int t = threadIdx.x;
  const int wid = t >> 6, lane = t & 63;
  const int col = lane & 15, kg = lane >> 4;
  const int b0 = blockIdx.x * 32;
  const int srow = t >> 3, sseg = t & 7;       // X staging coords
  const int wplane = t >> 7, oloc = t & 127;   // W staging coords

  float pCr[2][4], pCi[2][4];
  #pragma unroll
  for (int m = 0; m < 2; ++m)
    #pragma unroll
    for (int r = 0; r < 4; ++r) { pCr[m][r] = 0.f; pCi[m][r] = 0.f; }

  for (int c = 0; c < NCH; ++c) {
    __syncthreads();    // protect X LDS from previous channel's epilogue readers
    {   // stage Xi (plane 2c) and Xq (plane 2c+1): 64B per thread per plane, coalesced
      const u32x4* gi = (const u32x4*)(xplan + (size_t)(2*c)   * P_N + (size_t)(b0 + srow) * 256 + sseg * 32);
      const u32x4* gq = (const u32x4*)(xplan + (size_t)(2*c+1) * P_N + (size_t)(b0 + srow) * 256 + sseg * 32);
      u32x4 a0 = gi[0], a1 = gi[1], a2 = gi[2], a3 = gi[3];
      u32x4 q0 = gq[0], q1 = gq[1], q2 = gq[2], q3 = gq[3];
      *(u32x4*)&Xi[srow][sseg*32 +  0] = a0;
      *(u32x4*)&Xi[srow][sseg*32 +  8] = a1;
      *(u32x4*)&Xi[srow][sseg*32 + 16] = a2;
      *(u32x4*)&Xi[srow][sseg*32 + 24] = a3;
      *(u32x4*)&Xq[srow][sseg*32 +  0] = q0;
      *(u32x4*)&Xq[srow][sseg*32 +  8] = q1;
      *(u32x4*)&Xq[srow][sseg*32 + 16] = q2;
      *(u32x4*)&Xq[srow][sseg*32 + 24] = q3;
    }

    for (int oh = 0; oh < 2; ++oh) {        // o processed in 2 halves of 128
      f32x4 Srr[2][2], Sqi[2][2], Sqr[2][2], Sii[2][2];
      #pragma unroll
      for (int m = 0; m < 2; ++m)
        #pragma unroll
        for (int n = 0; n < 2; ++n) {
          Srr[m][n] = (f32x4){0.f,0.f,0.f,0.f};
          Sqi[m][n] = (f32x4){0.f,0.f,0.f,0.f};
          Sqr[m][n] = (f32x4){0.f,0.f,0.f,0.f};
          Sii[m][n] = (f32x4){0.f,0.f,0.f,0.f};
        }
      for (int k0 = 0; k0 < 256; k0 += 32) {
        __syncthreads();
        {   // stage W chunk: threads 0..127 -> Wr rows, 128..255 -> Wi rows
          const unsigned short* wsrc = wplane ? wi_bf : wr_bf;
          const u32x4* g = (const u32x4*)(wsrc + (size_t)(c * 256 + oh * 128 + oloc) * 256 + k0);
          u32x4 v0 = g[0], v1 = g[1], v2 = g[2], v3 = g[3];
          unsigned short (*dst)[40] = wplane ? Wil : Wrl;
          *(u32x4*)&dst[oloc][ 0] = v0;
          *(u32x4*)&dst[oloc][ 8] = v1;
          *(u32x4*)&dst[oloc][16] = v2;
          *(u32x4*)&dst[oloc][24] = v3;
        }
        __syncthreads();
        // A fragments: row = lane&15 (+16 for 2nd m-frag), k = k0 + kg*8 + j
        bf16x8 ari0 = *(const bf16x8*)&Xi[col     ][k0 + kg*8];
        bf16x8 ari1 = *(const bf16x8*)&Xi[16 + col][k0 + kg*8];
        bf16x8 aqi0 = *(const bf16x8*)&Xq[col     ][k0 + kg*8];
        bf16x8 aqi1 = *(const bf16x8*)&Xq[16 + col][k0 + kg*8];
        #pragma unroll
        for (int nf = 0; nf < 2; ++nf) {
          int orow = wid * 32 + nf * 16 + col;
          bf16x8 br = *(const bf16x8*)&Wrl[orow][kg*8];
          bf16x8 bi = *(const bf16x8*)&Wil[orow][kg*8];
          Srr[0][nf] = __builtin_amdgcn_mfma_f32_16x16x32_bf16(ari0, br, Srr[0][nf], 0,0,0);
          Srr[1][nf] = __builtin_amdgcn_mfma_f32_16x16x32_bf16(ari1, br, Srr[1][nf], 0,0,0);
          Sqr[0][nf] = __builtin_amdgcn_mfma_f32_16x16x32_bf16(aqi0, br, Sqr[0][nf], 0,0,0);
          Sqr[1][nf] = __builtin_amdgcn_mfma_f32_16x16x32_bf16(aqi1, br, Sqr[1][nf], 0,0,0);
          Sii[0][nf] = __builtin_amdgcn_mfma_f32_16x16x32_bf16(ari0, bi, Sii[0][nf], 0,0,0);
          Sii[1][nf] = __builtin_amdgcn_mfma_f32_16x16x32_bf16(ari1, bi, Sii[1][nf], 0,0,0);
          Sqi[0][nf] = __builtin_amdgcn_mfma_f32_16x16x32_bf16(aqi0, bi, Sqi[0][nf], 0,0,0);
          Sqi[1][nf] = __builtin_amdgcn_mfma_f32_16x16x32_bf16(aqi1, bi, Sqi[1][nf], 0,0,0);
        }
      }
      // epilogue: fold normalization affine + K terms, amp2 weighting, accumulate per-b
      float Ai  = AC[2*c],      Aq  = AC[2*c + 1];
      float Cin = AC[16 + 2*c], Cqn = AC[16 + 2*c + 1];
      #pragma unroll
      for (int nf = 0; nf < 2; ++nf) {
        int o = oh * 128 + wid * 32 + nf * 16 + col;
        int gidx = c * 256 + o;
        float kr = Kr[gidx], ki = Ki[gidx];
        float wfr = Wfr[gidx], wfi = Wfi[gidx];
        #pragma unroll
        for (int mf = 0; mf < 2; ++mf) {
          int bl = mf * 16 + kg * 4;
          #pragma unroll
          for (int r = 0; r < 4; ++r) {
            float cr = Ai * Srr[mf][nf][r] - Aq * Sqi[mf][nf][r] + kr;
            float ci = Aq * Sqr[mf][nf][r] + Ai * Sii[mf][nf][r] + ki;
            float xiv = Ai * bf2f(Xi[bl + r][o]) + Cin;
            float xqv = Aq * bf2f(Xq[bl + r][o]) + Cqn;
            float amp2 = xiv * xiv + xqv * xqv;
            pCr[mf][r] += amp2 * (cr * wfr - ci * wfi);
            pCi[mf][r] += amp2 * (ci * wfr + cr * wfi);
          }
        }
      }
    }
  }

  // sum over the 16 o-columns within each lane group
  #pragma unroll
  for (int off = 1; off < 16; off <<= 1) {
    #pragma unroll
    for (int m = 0; m < 2; ++m)
      #pragma unroll
      for (int r = 0; r < 4; ++r) {
        pCr[m][r] += __shfl_xor(pCr[m][r], off);
        pCi[m][r] += __shfl_xor(pCi[m][r], off);
      }
  }
  if (col == 0) {
    #pragma unroll
    for (int m = 0; m < 2; ++m)
      #pragma unroll
      for (int r = 0; r < 4; ++r) {
        red[wid][m*16 + kg*4 + r][0] = pCr[m][r];
        red[wid][m*16 + kg*4 + r][1] = pCi[m][r];
      }
  }
  __syncthreads();
  if (t < 64) {
    int bl = t >> 1, cc = t & 1;
    float v = red[0][bl][cc] + red[1][bl][cc] + red[2][bl][cc] + red[3][bl][cc];
    y[(size_t)(b0 + bl) * 2 + cc] = v;
  }
}

// ---------------- final batch LayerNorm over y (B,2) ----------------
__global__ __launch_bounds__(1024) void ln_kernel(
    const float* __restrict__ y, const float* __restrict__ g_out, const float* __restrict__ b_out,
    float* __restrict__ out)
{
  __shared__ float wsum[16][4];
  __shared__ float st[4];
  const int t = threadIdx.x;
  float s0 = 0.f, q0 = 0.f, s1 = 0.f, q1 = 0.f;
  for (int r = t; r < B_N; r += 1024) {
    float v0 = y[2*r], v1 = y[2*r + 1];
    s0 += v0; q0 += v0 * v0;
    s1 += v1; q1 += v1 * v1;
  }
  #pragma unroll
  for (int off = 32; off >= 1; off >>= 1) {
    s0 += __shfl_down(s0, off); q0 += __shfl_down(q0, off);
    s1 += __shfl_down(s1, off); q1 += __shfl_down(q1, off);
  }
  if ((t & 63) == 0) { int w = t >> 6; wsum[w][0]=s0; wsum[w][1]=q0; wsum[w][2]=s1; wsum[w][3]=q1; }
  __syncthreads();
  if (t == 0) {
    float S0=0.f,Q0=0.f,S1=0.f,Q1=0.f;
    for (int w = 0; w < 16; ++w) { S0+=wsum[w][0]; Q0+=wsum[w][1]; S1+=wsum[w][2]; Q1+=wsum[w][3]; }
    float n = (float)B_N;
    float mu0 = S0 / n, var0 = Q0 / n - mu0 * mu0;
    float mu1 = S1 / n, var1 = Q1 / n - mu1 * mu1;
    st[0] = mu0; st[1] = rsqrtf(var0 + EPS_F);
    st[2] = mu1; st[3] = rsqrtf(var1 + EPS_F);
  }
  __syncthreads();
  float g0 = g_out[0], g1 = g_out[1], bo0 = b_out[0], bo1 = b_out[1];
  float mu0 = st[0], rs0 = st[1], mu1 = st[2], rs1 = st[3];
  for (int r = t; r < B_N; r += 1024) {
    out[2*r]     = (y[2*r]     - mu0) * rs0 * g0 + bo0;
    out[2*r + 1] = (y[2*r + 1] - mu1) * rs1 * g1 + bo1;
  }
}

extern "C" void kernel_launch(void* const* d_in, const int* in_sizes, int n_in,
                              void* d_out, int out_size, void* d_ws, size_t ws_size,
                              hipStream_t stream) {
  (void)in_sizes; (void)n_in; (void)out_size; (void)ws_size;
  const float* x    = (const float*)d_in[0];
  // d_in[1] = h_0 (unused by the reference)
  const float* Wr   = (const float*)d_in[2];
  const float* Wi   = (const float*)d_in[3];
  const float* Wfr  = (const float*)d_in[4];
  const float* Wfi  = (const float*)d_in[5];
  const float* g_in = (const float*)d_in[6];
  const float* b_in = (const float*)d_in[7];
  const float* g_out= (const float*)d_in[8];
  const float* b_out= (const float*)d_in[9];
  float* out = (float*)d_out;

  char* ws = (char*)d_ws;
  float* stats = (float*)(ws + 0);            // 32 f
  float* AC    = (float*)(ws + 128);          // 32 f: A[16], C[16]
  float* RWr   = (float*)(ws + 256);          // 2048 f
  float* RWi   = (float*)(ws + 256 + 8192);
  float* Kr    = (float*)(ws + 256 + 16384);
  float* Ki    = (float*)(ws + 256 + 24576);
  float* y     = (float*)(ws + 33024);        // 32768 f (B x 2)
  unsigned short* wr_bf = (unsigned short*)(ws + 164096);             // 1 MB
  unsigned short* wi_bf = (unsigned short*)(ws + 164096 + 1048576);   // 1 MB
  unsigned short* xplan = (unsigned short*)(ws + 2261248);            // 128 MB: 16 planes of P_N bf16

  hipMemsetAsync(stats, 0, 128, stream);
  pass1_kernel<<<P_N / TP, 256, 0, stream>>>(x, xplan, stats);
  wprep_kernel<<<2048, 256, 0, stream>>>(Wr, Wi, wr_bf, wi_bf, RWr, RWi);
  finalize_kernel<<<1, 64, 0, stream>>>(stats, g_in, b_in, AC);
  kterm_kernel<<<8, 256, 0, stream>>>(AC, RWr, RWi, Kr, Ki);
  main_kernel<<<B_N / 32, 256, 0, stream>>>(xplan, wr_bf, wi_bf, AC, Kr, Ki, Wfr, Wfi, y);
  ln_kernel<<<1, 1024, 0, stream>>>(y, g_out, b_out, out);
}

// Round 2
// 267.604 us; speedup vs baseline: 3.8810x; 3.8810x over previous
//
#include <hip/hip_runtime.h>
#include <stdint.h>

#define B_N   16384
#define S_N   256
#define NCH   8
#define P_N   (B_N * S_N)      // 4194304 positions (b,s)
#define EPS_F 1e-5f

typedef float  f32x4  __attribute__((ext_vector_type(4)));
typedef __bf16 bf16x8 __attribute__((ext_vector_type(8)));
typedef unsigned int u32x4 __attribute__((ext_vector_type(4)));
typedef unsigned int u32x2 __attribute__((ext_vector_type(2)));

static __device__ __forceinline__ unsigned short f2bf(float f) {
  union { float f; unsigned u; } v; v.f = f;
  unsigned u = v.u;
  u += 0x7fffu + ((u >> 16) & 1u);          // RNE
  return (unsigned short)(u >> 16);
}
static __device__ __forceinline__ float bf2f(unsigned short h) {
  union { unsigned u; float f; } v; v.u = ((unsigned)h) << 16;
  return v.f;
}

// ---------------- pass 1: per-channel stats partials + planar bf16 transpose ----------------
// x (B,S,16) fp32 -> xplan[16][P_N] bf16 (raw), partials[2048][32] = per-block {sum[16], sumsq[16]}
// No LDS transpose: thread owns channel-quad (t&3) x 8 consecutive positions; packs pairs
// into u32 and stores u32x4 per channel (16 lanes/plane -> 256B contiguous segments).
__global__ __launch_bounds__(256) void pass1_kernel(
    const float* __restrict__ x, unsigned short* __restrict__ xplan,
    float* __restrict__ partials)
{
  __shared__ float ps[4][32];
  const int t = threadIdx.x;
  const int q = t & 3;               // channel quad: interleaved channels 4q..4q+3
  const int pg = t >> 2;             // 0..63 position-group within tile
  float s[4] = {0.f,0.f,0.f,0.f}, ss[4] = {0.f,0.f,0.f,0.f};
  const f32x4* xv = (const f32x4*)x;

  for (int it = 0; it < 4; ++it) {
    size_t p0 = ((size_t)blockIdx.x * 4 + it) * 512 + (size_t)pg * 8;
    f32x4 v[8];
    #pragma unroll
    for (int j = 0; j < 8; ++j) v[j] = xv[(p0 + j) * 4 + q];
    #pragma unroll
    for (int j = 0; j < 8; ++j)
      #pragma unroll
      for (int k = 0; k < 4; ++k) { s[k] += v[j][k]; ss[k] += v[j][k] * v[j][k]; }
    #pragma unroll
    for (int j2 = 0; j2 < 4; ++j2) {
      u32x4 w;
      #pragma unroll
      for (int k = 0; k < 4; ++k)
        w[k] = (unsigned)f2bf(v[2*k][j2]) | ((unsigned)f2bf(v[2*k+1][j2]) << 16);
      *(u32x4*)(xplan + (size_t)(q * 4 + j2) * P_N + p0) = w;
    }
  }

  // wave reduce to lanes 0..3 (lane l keeps quad l; offsets preserve t&3)
  #pragma unroll
  for (int off = 32; off >= 4; off >>= 1) {
    #pragma unroll
    for (int k = 0; k < 4; ++k) { s[k] += __shfl_down(s[k], off); ss[k] += __shfl_down(ss[k], off); }
  }
  const int lane = t & 63, wid = t >> 6;
  if (lane < 4) {
    #pragma unroll
    for (int k = 0; k < 4; ++k) {
      ps[wid][lane * 4 + k]      = s[k];
      ps[wid][16 + lane * 4 + k] = ss[k];
    }
  }
  __syncthreads();
  if (t < 32)
    partials[blockIdx.x * 32 + t] = ps[0][t] + ps[1][t] + ps[2][t] + ps[3][t];
}

// ---------------- finalize: reduce partials -> A,C ----------------
__global__ __launch_bounds__(1024) void finalize_kernel(
    const float* __restrict__ partials, const float* __restrict__ g_in,
    const float* __restrict__ b_in, float* __restrict__ AC)
{
  __shared__ float acc[32][32];
  const int t = threadIdx.x;
  const int v = t & 31, chunk = t >> 5;
  float s = 0.f;
  for (int i = 0; i < 64; ++i)
    s += partials[(size_t)(chunk * 64 + i) * 32 + v];
  acc[chunk][v] = s;
  __syncthreads();
  if (t < 32) {
    float tot = 0.f;
    #pragma unroll
    for (int k = 0; k < 32; ++k) tot += acc[k][t];
    acc[0][t] = tot;           // single wave: lockstep, reads complete before write
  }
  __syncthreads();
  if (t < 16) {
    float n = (float)P_N;
    float mu  = acc[0][t] / n;
    float var = acc[0][16 + t] / n - mu * mu;
    float A = g_in[t] * rsqrtf(var + EPS_F);
    AC[t] = A;
    AC[16 + t] = b_in[t] - mu * A;
  }
}

// ---------------- W prep: fp32 -> bf16 + rowsums ----------------
__global__ __launch_bounds__(256) void wprep_kernel(
    const float* __restrict__ Wr, const float* __restrict__ Wi,
    unsigned short* __restrict__ wr_bf, unsigned short* __restrict__ wi_bf,
    float* __restrict__ RWr, float* __restrict__ RWi)
{
  __shared__ float sr[4], si[4];
  const int row = blockIdx.x, t = threadIdx.x;   // row = c*256 + o
  const size_t idx = (size_t)row * 256 + t;
  float vr = Wr[idx], vi = Wi[idx];
  wr_bf[idx] = f2bf(vr);
  wi_bf[idx] = f2bf(vi);
  float rr = vr, ri = vi;
  #pragma unroll
  for (int off = 32; off >= 1; off >>= 1) { rr += __shfl_down(rr, off); ri += __shfl_down(ri, off); }
  if ((t & 63) == 0) { sr[t >> 6] = rr; si[t >> 6] = ri; }
  __syncthreads();
  if (t == 0) {
    RWr[row] = sr[0] + sr[1] + sr[2] + sr[3];
    RWi[row] = si[0] + si[1] + si[2] + si[3];
  }
}

// ---------------- K terms: Kr = Ci*RWr - Cq*RWi ; Ki = Cq*RWr + Ci*RWi ----------------
__global__ __launch_bounds__(256) void kterm_kernel(
    const float* __restrict__ AC, const float* __restrict__ RWr, const float* __restrict__ RWi,
    float* __restrict__ Kr, float* __restrict__ Ki)
{
  int idx = blockIdx.x * 256 + threadIdx.x;   // 2048 = c*256+o
  int c = idx >> 8;
  float Ci_ = AC[16 + 2*c], Cq_ = AC[16 + 2*c + 1];
  Kr[idx] = Ci_ * RWr[idx] - Cq_ * RWi[idx];
  Ki[idx] = Cq_ * RWr[idx] + Ci_ * RWi[idx];
}

// ---------------- main: per-channel complex MFMA matmul + amp2-weighted contraction ----------------
// block = 256 thr (4 waves), 32 batch rows; waves tile o; K-chunks of 64 staged in LDS.
__global__ __launch_bounds__(256, 2) void main_kernel(
    const unsigned short* __restrict__ xplan,
    const unsigned short* __restrict__ wr_bf,
    const unsigned short* __restrict__ wi_bf,
    const float* __restrict__ AC,
    const float* __restrict__ Kr, const float* __restrict__ Ki,
    const float* __restrict__ Wfr, const float* __restrict__ Wfi,
    float* __restrict__ y)
{
  __shared__ unsigned short Xi[32][264];   // +8 pad
  __shared__ unsigned short Xq[32][264];
  __shared__ unsigned short Wrl[128][72];  // 64 k + 8 pad
  __shared__ unsigned short Wil[128][72];
  __shared__ float red[4][32][2];

  const int t = threadIdx.x;
  const int wid = t >> 6, lane = t & 63;
  const int col = lane & 15, kg = lane >> 4;
  const int b0 = blockIdx.x * 32;
  const int srow = t >> 3, sseg = t & 7;       // X staging coords
  const int wplane = t >> 7, oloc = t & 127;   // W staging coords

  float pCr[2][4], pCi[2][4];
  #pragma unroll
  for (int m = 0; m < 2; ++m)
    #pragma unroll
    for (int r = 0; r < 4; ++r) { pCr[m][r] = 0.f; pCi[m][r] = 0.f; }

  for (int c = 0; c < NCH; ++c) {
    __syncthreads();    // protect X LDS from previous channel's epilogue readers
    {   // stage Xi (plane 2c) and Xq (plane 2c+1): 64B per thread per plane, coalesced
      const u32x4* gi = (const u32x4*)(xplan + (size_t)(2*c)   * P_N + (size_t)(b0 + srow) * 256 + sseg * 32);
      const u32x4* gq = (const u32x4*)(xplan + (size_t)(2*c+1) * P_N + (size_t)(b0 + srow) * 256 + sseg * 32);
      u32x4 a0 = gi[0], a1 = gi[1], a2 = gi[2], a3 = gi[3];
      u32x4 q0 = gq[0], q1 = gq[1], q2 = gq[2], q3 = gq[3];
      *(u32x4*)&Xi[srow][sseg*32 +  0] = a0;
      *(u32x4*)&Xi[srow][sseg*32 +  8] = a1;
      *(u32x4*)&Xi[srow][sseg*32 + 16] = a2;
      *(u32x4*)&Xi[srow][sseg*32 + 24] = a3;
      *(u32x4*)&Xq[srow][sseg*32 +  0] = q0;
      *(u32x4*)&Xq[srow][sseg*32 +  8] = q1;
      *(u32x4*)&Xq[srow][sseg*32 + 16] = q2;
      *(u32x4*)&Xq[srow][sseg*32 + 24] = q3;
    }

    for (int oh = 0; oh < 2; ++oh) {        // o processed in 2 halves of 128
      f32x4 Srr[2][2], Sqi[2][2], Sqr[2][2], Sii[2][2];
      #pragma unroll
      for (int m = 0; m < 2; ++m)
        #pragma unroll
        for (int n = 0; n < 2; ++n) {
          Srr[m][n] = (f32x4){0.f,0.f,0.f,0.f};
          Sqi[m][n] = (f32x4){0.f,0.f,0.f,0.f};
          Sqr[m][n] = (f32x4){0.f,0.f,0.f,0.f};
          Sii[m][n] = (f32x4){0.f,0.f,0.f,0.f};
        }
      for (int k0 = 0; k0 < 256; k0 += 64) {
        __syncthreads();
        {   // stage W chunk (64 k): threads 0..127 -> Wr rows, 128..255 -> Wi rows
          const unsigned short* wsrc = wplane ? wi_bf : wr_bf;
          const u32x4* g = (const u32x4*)(wsrc + (size_t)(c * 256 + oh * 128 + oloc) * 256 + k0);
          u32x4 v0 = g[0], v1 = g[1], v2 = g[2], v3 = g[3];
          u32x4 v4 = g[4], v5 = g[5], v6 = g[6], v7 = g[7];
          unsigned short (*dst)[72] = wplane ? Wil : Wrl;
          *(u32x4*)&dst[oloc][ 0] = v0;
          *(u32x4*)&dst[oloc][ 8] = v1;
          *(u32x4*)&dst[oloc][16] = v2;
          *(u32x4*)&dst[oloc][24] = v3;
          *(u32x4*)&dst[oloc][32] = v4;
          *(u32x4*)&dst[oloc][40] = v5;
          *(u32x4*)&dst[oloc][48] = v6;
          *(u32x4*)&dst[oloc][56] = v7;
        }
        __syncthreads();
        #pragma unroll
        for (int kk = 0; kk < 64; kk += 32) {
          // A fragments: row = lane&15 (+16 for 2nd m-frag), k = k0 + kk + kg*8 + j
          bf16x8 ari0 = *(const bf16x8*)&Xi[col     ][k0 + kk + kg*8];
          bf16x8 ari1 = *(const bf16x8*)&Xi[16 + col][k0 + kk + kg*8];
          bf16x8 aqi0 = *(const bf16x8*)&Xq[col     ][k0 + kk + kg*8];
          bf16x8 aqi1 = *(const bf16x8*)&Xq[16 + col][k0 + kk + kg*8];
          #pragma unroll
          for (int nf = 0; nf < 2; ++nf) {
            int orow = wid * 32 + nf * 16 + col;
            bf16x8 br = *(const bf16x8*)&Wrl[orow][kk + kg*8];
            bf16x8 bi = *(const bf16x8*)&Wil[orow][kk + kg*8];
            Srr[0][nf] = __builtin_amdgcn_mfma_f32_16x16x32_bf16(ari0, br, Srr[0][nf], 0,0,0);
            Srr[1][nf] = __builtin_amdgcn_mfma_f32_16x16x32_bf16(ari1, br, Srr[1][nf], 0,0,0);
            Sqr[0][nf] = __builtin_amdgcn_mfma_f32_16x16x32_bf16(aqi0, br, Sqr[0][nf], 0,0,0);
            Sqr[1][nf] = __builtin_amdgcn_mfma_f32_16x16x32_bf16(aqi1, br, Sqr[1][nf], 0,0,0);
            Sii[0][nf] = __builtin_amdgcn_mfma_f32_16x16x32_bf16(ari0, bi, Sii[0][nf], 0,0,0);
            Sii[1][nf] = __builtin_amdgcn_mfma_f32_16x16x32_bf16(ari1, bi, Sii[1][nf], 0,0,0);
            Sqi[0][nf] = __builtin_amdgcn_mfma_f32_16x16x32_bf16(aqi0, bi, Sqi[0][nf], 0,0,0);
            Sqi[1][nf] = __builtin_amdgcn_mfma_f32_16x16x32_bf16(aqi1, bi, Sqi[1][nf], 0,0,0);
          }
        }
      }
      // epilogue: fold normalization affine + K terms, amp2 weighting, accumulate per-b
      float Ai  = AC[2*c],      Aq  = AC[2*c + 1];
      float Cin = AC[16 + 2*c], Cqn = AC[16 + 2*c + 1];
      #pragma unroll
      for (int nf = 0; nf < 2; ++nf) {
        int o = oh * 128 + wid * 32 + nf * 16 + col;
        int gidx = c * 256 + o;
        float kr = Kr[gidx], ki = Ki[gidx];
        float wfr = Wfr[gidx], wfi = Wfi[gidx];
        #pragma unroll
        for (int mf = 0; mf < 2; ++mf) {
          int bl = mf * 16 + kg * 4;
          #pragma unroll
          for (int r = 0; r < 4; ++r) {
            float cr = Ai * Srr[mf][nf][r] - Aq * Sqi[mf][nf][r] + kr;
            float ci = Aq * Sqr[mf][nf][r] + Ai * Sii[mf][nf][r] + ki;
            float xiv = Ai * bf2f(Xi[bl + r][o]) + Cin;
            float xqv = Aq * bf2f(Xq[bl + r][o]) + Cqn;
            float amp2 = xiv * xiv + xqv * xqv;
            pCr[mf][r] += amp2 * (cr * wfr - ci * wfi);
            pCi[mf][r] += amp2 * (ci * wfr + cr * wfi);
          }
        }
      }
    }
  }

  // sum over the 16 o-columns within each lane group
  #pragma unroll
  for (int off = 1; off < 16; off <<= 1) {
    #pragma unroll
    for (int m = 0; m < 2; ++m)
      #pragma unroll
      for (int r = 0; r < 4; ++r) {
        pCr[m][r] += __shfl_xor(pCr[m][r], off);
        pCi[m][r] += __shfl_xor(pCi[m][r], off);
      }
  }
  if (col == 0) {
    #pragma unroll
    for (int m = 0; m < 2; ++m)
      #pragma unroll
      for (int r = 0; r < 4; ++r) {
        red[wid][m*16 + kg*4 + r][0] = pCr[m][r];
        red[wid][m*16 + kg*4 + r][1] = pCi[m][r];
      }
  }
  __syncthreads();
  if (t < 64) {
    int bl = t >> 1, cc = t & 1;
    float v = red[0][bl][cc] + red[1][bl][cc] + red[2][bl][cc] + red[3][bl][cc];
    y[(size_t)(b0 + bl) * 2 + cc] = v;
  }
}

// ---------------- final batch LayerNorm over y (B,2) ----------------
__global__ __launch_bounds__(1024) void ln_kernel(
    const float* __restrict__ y, const float* __restrict__ g_out, const float* __restrict__ b_out,
    float* __restrict__ out)
{
  __shared__ float wsum[16][4];
  __shared__ float st[4];
  const int t = threadIdx.x;
  float s0 = 0.f, q0 = 0.f, s1 = 0.f, q1 = 0.f;
  for (int r = t; r < B_N; r += 1024) {
    float v0 = y[2*r], v1 = y[2*r + 1];
    s0 += v0; q0 += v0 * v0;
    s1 += v1; q1 += v1 * v1;
  }
  #pragma unroll
  for (int off = 32; off >= 1; off >>= 1) {
    s0 += __shfl_down(s0, off); q0 += __shfl_down(q0, off);
    s1 += __shfl_down(s1, off); q1 += __shfl_down(q1, off);
  }
  if ((t & 63) == 0) { int w = t >> 6; wsum[w][0]=s0; wsum[w][1]=q0; wsum[w][2]=s1; wsum[w][3]=q1; }
  __syncthreads();
  if (t == 0) {
    float S0=0.f,Q0=0.f,S1=0.f,Q1=0.f;
    for (int w = 0; w < 16; ++w) { S0+=wsum[w][0]; Q0+=wsum[w][1]; S1+=wsum[w][2]; Q1+=wsum[w][3]; }
    float n = (float)B_N;
    float mu0 = S0 / n, var0 = Q0 / n - mu0 * mu0;
    float mu1 = S1 / n, var1 = Q1 / n - mu1 * mu1;
    st[0] = mu0; st[1] = rsqrtf(var0 + EPS_F);
    st[2] = mu1; st[3] = rsqrtf(var1 + EPS_F);
  }
  __syncthreads();
  float g0 = g_out[0], g1 = g_out[1], bo0 = b_out[0], bo1 = b_out[1];
  float mu0 = st[0], rs0 = st[1], mu1 = st[2], rs1 = st[3];
  for (int r = t; r < B_N; r += 1024) {
    out[2*r]     = (y[2*r]     - mu0) * rs0 * g0 + bo0;
    out[2*r + 1] = (y[2*r + 1] - mu1) * rs1 * g1 + bo1;
  }
}

extern "C" void kernel_launch(void* const* d_in, const int* in_sizes, int n_in,
                              void* d_out, int out_size, void* d_ws, size_t ws_size,
                              hipStream_t stream) {
  (void)in_sizes; (void)n_in; (void)out_size; (void)ws_size;
  const float* x    = (const float*)d_in[0];
  // d_in[1] = h_0 (unused by the reference)
  const float* Wr   = (const float*)d_in[2];
  const float* Wi   = (const float*)d_in[3];
  const float* Wfr  = (const float*)d_in[4];
  const float* Wfi  = (const float*)d_in[5];
  const float* g_in = (const float*)d_in[6];
  const float* b_in = (const float*)d_in[7];
  const float* g_out= (const float*)d_in[8];
  const float* b_out= (const float*)d_in[9];
  float* out = (float*)d_out;

  char* ws = (char*)d_ws;
  float* AC    = (float*)(ws + 128);          // 32 f: A[16], C[16]
  float* RWr   = (float*)(ws + 256);          // 2048 f
  float* RWi   = (float*)(ws + 256 + 8192);
  float* Kr    = (float*)(ws + 256 + 16384);
  float* Ki    = (float*)(ws + 256 + 24576);
  float* y     = (float*)(ws + 33024);        // 32768 f (B x 2)
  // partials overlaps wr_bf: finalize consumes it BEFORE wprep writes wr_bf (same stream order)
  float* partials = (float*)(ws + 164096);    // 2048*32 f = 256 KB
  unsigned short* wr_bf = (unsigned short*)(ws + 164096);             // 1 MB
  unsigned short* wi_bf = (unsigned short*)(ws + 164096 + 1048576);   // 1 MB
  unsigned short* xplan = (unsigned short*)(ws + 2261248);            // 128 MB: 16 planes of P_N bf16

  pass1_kernel<<<2048, 256, 0, stream>>>(x, xplan, partials);
  finalize_kernel<<<1, 1024, 0, stream>>>(partials, g_in, b_in, AC);
  wprep_kernel<<<2048, 256, 0, stream>>>(Wr, Wi, wr_bf, wi_bf, RWr, RWi);
  kterm_kernel<<<8, 256, 0, stream>>>(AC, RWr, RWi, Kr, Ki);
  main_kernel<<<B_N / 32, 256, 0, stream>>>(xplan, wr_bf, wi_bf, AC, Kr, Ki, Wfr, Wfi, y);
  ln_kernel<<<1, 1024, 0, stream>>>(y, g_out, b_out, out);
}

// Round 3
// 206.920 us; speedup vs baseline: 5.0193x; 1.2933x over previous
//
#include <hip/hip_runtime.h>
#include <stdint.h>

#define B_N   16384
#define S_N   256
#define NCH   8
#define P_N   (B_N * S_N)      // 4194304 positions (b,s)
#define EPS_F 1e-5f

typedef float  f32x4  __attribute__((ext_vector_type(4)));
typedef __bf16 bf16x8 __attribute__((ext_vector_type(8)));
typedef unsigned int u32x4 __attribute__((ext_vector_type(4)));
typedef unsigned int u32x2 __attribute__((ext_vector_type(2)));

static __device__ __forceinline__ unsigned short f2bf(float f) {
  union { float f; unsigned u; } v; v.f = f;
  unsigned u = v.u;
  u += 0x7fffu + ((u >> 16) & 1u);          // RNE
  return (unsigned short)(u >> 16);
}
static __device__ __forceinline__ float bf2f(unsigned short h) {
  union { unsigned u; float f; } v; v.u = ((unsigned)h) << 16;
  return v.f;
}

typedef const __attribute__((address_space(1))) unsigned int* gas1_t;
typedef __attribute__((address_space(3))) unsigned int* las3_t;
// async global->LDS, 16B per lane; LDS dest must be linear (base + lane*16)
static __device__ __forceinline__ void gl16(const void* g, void* l) {
  __builtin_amdgcn_global_load_lds((gas1_t)(uintptr_t)g,
                                   (las3_t)(unsigned int)(uintptr_t)l, 16, 0, 0);
}

// ---------------- pass 1: per-channel stats partials + planar bf16 transpose ----------------
__global__ __launch_bounds__(256) void pass1_kernel(
    const float* __restrict__ x, unsigned short* __restrict__ xplan,
    float* __restrict__ partials)
{
  __shared__ float ps[4][32];
  const int t = threadIdx.x;
  const int q = t & 3;               // channel quad: interleaved channels 4q..4q+3
  const int pg = t >> 2;             // 0..63 position-group within tile
  float s[4] = {0.f,0.f,0.f,0.f}, ss[4] = {0.f,0.f,0.f,0.f};
  const f32x4* xv = (const f32x4*)x;

  for (int it = 0; it < 4; ++it) {
    size_t p0 = ((size_t)blockIdx.x * 4 + it) * 512 + (size_t)pg * 8;
    f32x4 v[8];
    #pragma unroll
    for (int j = 0; j < 8; ++j) v[j] = xv[(p0 + j) * 4 + q];
    #pragma unroll
    for (int j = 0; j < 8; ++j)
      #pragma unroll
      for (int k = 0; k < 4; ++k) { s[k] += v[j][k]; ss[k] += v[j][k] * v[j][k]; }
    #pragma unroll
    for (int j2 = 0; j2 < 4; ++j2) {
      u32x4 w;
      #pragma unroll
      for (int k = 0; k < 4; ++k)
        w[k] = (unsigned)f2bf(v[2*k][j2]) | ((unsigned)f2bf(v[2*k+1][j2]) << 16);
      *(u32x4*)(xplan + (size_t)(q * 4 + j2) * P_N + p0) = w;
    }
  }

  #pragma unroll
  for (int off = 32; off >= 4; off >>= 1) {
    #pragma unroll
    for (int k = 0; k < 4; ++k) { s[k] += __shfl_down(s[k], off); ss[k] += __shfl_down(ss[k], off); }
  }
  const int lane = t & 63, wid = t >> 6;
  if (lane < 4) {
    #pragma unroll
    for (int k = 0; k < 4; ++k) {
      ps[wid][lane * 4 + k]      = s[k];
      ps[wid][16 + lane * 4 + k] = ss[k];
    }
  }
  __syncthreads();
  if (t < 32)
    partials[blockIdx.x * 32 + t] = ps[0][t] + ps[1][t] + ps[2][t] + ps[3][t];
}

// ---------------- finalize: reduce partials -> A,C ----------------
__global__ __launch_bounds__(1024) void finalize_kernel(
    const float* __restrict__ partials, const float* __restrict__ g_in,
    const float* __restrict__ b_in, float* __restrict__ AC)
{
  __shared__ float acc[32][32];
  const int t = threadIdx.x;
  const int v = t & 31, chunk = t >> 5;
  float s = 0.f;
  for (int i = 0; i < 64; ++i)
    s += partials[(size_t)(chunk * 64 + i) * 32 + v];
  acc[chunk][v] = s;
  __syncthreads();
  if (t < 32) {
    float tot = 0.f;
    #pragma unroll
    for (int k = 0; k < 32; ++k) tot += acc[k][t];
    acc[0][t] = tot;
  }
  __syncthreads();
  if (t < 16) {
    float n = (float)P_N;
    float mu  = acc[0][t] / n;
    float var = acc[0][16 + t] / n - mu * mu;
    float A = g_in[t] * rsqrtf(var + EPS_F);
    AC[t] = A;
    AC[16 + t] = b_in[t] - mu * A;
  }
}

// ---------------- W prep: fp32 -> bf16 + rowsums ----------------
__global__ __launch_bounds__(256) void wprep_kernel(
    const float* __restrict__ Wr, const float* __restrict__ Wi,
    unsigned short* __restrict__ wr_bf, unsigned short* __restrict__ wi_bf,
    float* __restrict__ RWr, float* __restrict__ RWi)
{
  __shared__ float sr[4], si[4];
  const int row = blockIdx.x, t = threadIdx.x;   // row = c*256 + o
  const size_t idx = (size_t)row * 256 + t;
  float vr = Wr[idx], vi = Wi[idx];
  wr_bf[idx] = f2bf(vr);
  wi_bf[idx] = f2bf(vi);
  float rr = vr, ri = vi;
  #pragma unroll
  for (int off = 32; off >= 1; off >>= 1) { rr += __shfl_down(rr, off); ri += __shfl_down(ri, off); }
  if ((t & 63) == 0) { sr[t >> 6] = rr; si[t >> 6] = ri; }
  __syncthreads();
  if (t == 0) {
    RWr[row] = sr[0] + sr[1] + sr[2] + sr[3];
    RWi[row] = si[0] + si[1] + si[2] + si[3];
  }
}

// ---------------- K terms ----------------
__global__ __launch_bounds__(256) void kterm_kernel(
    const float* __restrict__ AC, const float* __restrict__ RWr, const float* __restrict__ RWi,
    float* __restrict__ Kr, float* __restrict__ Ki)
{
  int idx = blockIdx.x * 256 + threadIdx.x;   // 2048 = c*256+o
  int c = idx >> 8;
  float Ci_ = AC[16 + 2*c], Cq_ = AC[16 + 2*c + 1];
  Kr[idx] = Ci_ * RWr[idx] - Cq_ * RWi[idx];
  Ki[idx] = Cq_ * RWr[idx] + Ci_ * RWi[idx];
}

// W chunk stage: 16KB = 128 o-rows x 128B (Wr|Wi 16B-granules interleaved, XOR-swizzled)
static __device__ __forceinline__ void issue_w(
    const unsigned short* __restrict__ wr_bf, const unsigned short* __restrict__ wi_bf,
    int c, int u, char* wbuf, int t)
{
  const int oh = u >> 3, c32 = u & 7;
  #pragma unroll
  for (int i = 0; i < 4; ++i) {
    const int L = i * 4096 + t * 16;            // linear LDS byte (lane*16 within wave)
    const int row = i * 32 + (t >> 3);          // o-row 0..127
    const int ds_ = (t & 7) ^ (row & 7);        // data granule: plane = ds_>>2, kslot = ds_&3
    const unsigned short* wb = (ds_ & 4) ? wi_bf : wr_bf;
    const char* g = (const char*)(wb + (size_t)(c * 256 + oh * 128 + row) * 256
                                     + c32 * 32 + (ds_ & 3) * 8);
    gl16(g, wbuf + L);
  }
}

// ---------------- main: complex MFMA matmul + amp2-weighted contraction ----------------
// 512 blocks x 256 thr; 32 batch rows/block; W double-buffered k=32 chunks w/ prefetch-1.
__global__ __launch_bounds__(256, 2) void main_kernel(
    const unsigned short* __restrict__ xplan,
    const unsigned short* __restrict__ wr_bf,
    const unsigned short* __restrict__ wi_bf,
    const float* __restrict__ AC,
    const float* __restrict__ Kr, const float* __restrict__ Ki,
    const float* __restrict__ Wfr, const float* __restrict__ Wfi,
    float* __restrict__ y)
{
  __shared__ char Xlds[32768];     // 2 planes x 32 rows x 512B, 16B-granule XOR swizzle (row&7)
  __shared__ char Wlds[2][16384];  // dbuf
  __shared__ float red[4][32][2];

  const int t = threadIdx.x;
  const int wid = t >> 6, lane = t & 63;
  const int col = lane & 15, kg = lane >> 4;
  const int b0 = blockIdx.x * 32;

  float pCr[2][4], pCi[2][4];
  #pragma unroll
  for (int m = 0; m < 2; ++m)
    #pragma unroll
    for (int r = 0; r < 4; ++r) { pCr[m][r] = 0.f; pCi[m][r] = 0.f; }

  int cur = 0;
  for (int c = 0; c < NCH; ++c) {
    // stage X planes (Xi = plane 2c, Xq = plane 2c+1) + first W chunk, then drain
    #pragma unroll
    for (int i = 0; i < 8; ++i) {
      const int plane = i >> 2, si = i & 3;
      const int L = plane * 16384 + si * 4096 + t * 16;
      const int row = si * 8 + (t >> 5);              // batch row 0..31
      const int gd = (t & 31) ^ (row & 7);            // data granule at this slot
      const char* g = (const char*)xplan
          + (((size_t)(2 * c + plane) * P_N + (size_t)(b0 + row) * 256) << 1) + (gd << 4);
      gl16(g, &Xlds[L]);
    }
    issue_w(wr_bf, wi_bf, c, 0, &Wlds[cur][0], t);
    __syncthreads();   // implicit vmcnt(0): X + chunk0 ready

    for (int oh = 0; oh < 2; ++oh) {
      f32x4 Srr[2][2], Sqi[2][2], Sqr[2][2], Sii[2][2];
      #pragma unroll
      for (int m = 0; m < 2; ++m)
        #pragma unroll
        for (int n = 0; n < 2; ++n) {
          Srr[m][n] = (f32x4){0.f,0.f,0.f,0.f};
          Sqi[m][n] = (f32x4){0.f,0.f,0.f,0.f};
          Sqr[m][n] = (f32x4){0.f,0.f,0.f,0.f};
          Sii[m][n] = (f32x4){0.f,0.f,0.f,0.f};
        }
      #pragma unroll
      for (int t7 = 0; t7 < 8; ++t7) {
        const int u = oh * 8 + t7;
        if (u < 15) issue_w(wr_bf, wi_bf, c, u + 1, &Wlds[cur ^ 1][0], t);  // prefetch next

        // A frags: rows col / 16+col (same &7), k-granule = chunk*4 + kg
        const int axo = ((((u & 7) * 4 + kg) ^ (col & 7)) << 4);
        const char* XiP = Xlds;
        const char* XqP = Xlds + 16384;
        bf16x8 ari0 = *(const bf16x8*)(XiP + col * 512 + axo);
        bf16x8 ari1 = *(const bf16x8*)(XiP + (16 + col) * 512 + axo);
        bf16x8 aqi0 = *(const bf16x8*)(XqP + col * 512 + axo);
        bf16x8 aqi1 = *(const bf16x8*)(XqP + (16 + col) * 512 + axo);
        const char* Wb = &Wlds[cur][0];
        #pragma unroll
        for (int nf = 0; nf < 2; ++nf) {
          const int r = wid * 32 + nf * 16 + col;
          bf16x8 br = *(const bf16x8*)(Wb + r * 128 + (((kg    ) ^ (r & 7)) << 4));
          bf16x8 bi = *(const bf16x8*)(Wb + r * 128 + (((kg + 4) ^ (r & 7)) << 4));
          Srr[0][nf] = __builtin_amdgcn_mfma_f32_16x16x32_bf16(ari0, br, Srr[0][nf], 0,0,0);
          Srr[1][nf] = __builtin_amdgcn_mfma_f32_16x16x32_bf16(ari1, br, Srr[1][nf], 0,0,0);
          Sqr[0][nf] = __builtin_amdgcn_mfma_f32_16x16x32_bf16(aqi0, br, Sqr[0][nf], 0,0,0);
          Sqr[1][nf] = __builtin_amdgcn_mfma_f32_16x16x32_bf16(aqi1, br, Sqr[1][nf], 0,0,0);
          Sii[0][nf] = __builtin_amdgcn_mfma_f32_16x16x32_bf16(ari0, bi, Sii[0][nf], 0,0,0);
          Sii[1][nf] = __builtin_amdgcn_mfma_f32_16x16x32_bf16(ari1, bi, Sii[1][nf], 0,0,0);
          Sqi[0][nf] = __builtin_amdgcn_mfma_f32_16x16x32_bf16(aqi0, bi, Sqi[0][nf], 0,0,0);
          Sqi[1][nf] = __builtin_amdgcn_mfma_f32_16x16x32_bf16(aqi1, bi, Sqi[1][nf], 0,0,0);
        }
        __syncthreads();   // drains prefetch (vmcnt 0) + protects buffer swap
        cur ^= 1;
      }

      // epilogue: fold affine + K terms, amp2 weighting, accumulate per-b
      const float Ai_ = AC[2*c],      Aq_ = AC[2*c + 1];
      const float Cin = AC[16 + 2*c], Cqn = AC[16 + 2*c + 1];
      #pragma unroll
      for (int nf = 0; nf < 2; ++nf) {
        const int o = oh * 128 + wid * 32 + nf * 16 + col;
        const int gidx = c * 256 + o;
        const float kr = Kr[gidx], ki = Ki[gidx];
        const float wfr = Wfr[gidx], wfi = Wfi[gidx];
        const int og = o >> 3, ob = (o & 7) * 2;
        #pragma unroll
        for (int mf = 0; mf < 2; ++mf) {
          const int bl = mf * 16 + kg * 4;
          #pragma unroll
          for (int r = 0; r < 4; ++r) {
            const int row = bl + r;
            const int sb = row * 512 + ((og ^ (row & 7)) << 4) + ob;
            float xiv = Ai_ * bf2f(*(const unsigned short*)(Xlds + sb)) + Cin;
            float xqv = Aq_ * bf2f(*(const unsigned short*)(Xlds + 16384 + sb)) + Cqn;
            float cr = Ai_ * Srr[mf][nf][r] - Aq_ * Sqi[mf][nf][r] + kr;
            float ci = Aq_ * Sqr[mf][nf][r] + Ai_ * Sii[mf][nf][r] + ki;
            float amp2 = xiv * xiv + xqv * xqv;
            pCr[mf][r] += amp2 * (cr * wfr - ci * wfi);
            pCi[mf][r] += amp2 * (ci * wfr + cr * wfi);
          }
        }
      }
    }
    __syncthreads();   // protect X LDS before next channel's staging
  }

  // sum over the 16 o-columns within each lane group
  #pragma unroll
  for (int off = 1; off < 16; off <<= 1) {
    #pragma unroll
    for (int m = 0; m < 2; ++m)
      #pragma unroll
      for (int r = 0; r < 4; ++r) {
        pCr[m][r] += __shfl_xor(pCr[m][r], off);
        pCi[m][r] += __shfl_xor(pCi[m][r], off);
      }
  }
  if (col == 0) {
    #pragma unroll
    for (int m = 0; m < 2; ++m)
      #pragma unroll
      for (int r = 0; r < 4; ++r) {
        red[wid][m*16 + kg*4 + r][0] = pCr[m][r];
        red[wid][m*16 + kg*4 + r][1] = pCi[m][r];
      }
  }
  __syncthreads();
  if (t < 64) {
    int bl = t >> 1, cc = t & 1;
    float v = red[0][bl][cc] + red[1][bl][cc] + red[2][bl][cc] + red[3][bl][cc];
    y[(size_t)(b0 + bl) * 2 + cc] = v;
  }
}

// ---------------- final batch LayerNorm over y (B,2) ----------------
__global__ __launch_bounds__(1024) void ln_kernel(
    const float* __restrict__ y, const float* __restrict__ g_out, const float* __restrict__ b_out,
    float* __restrict__ out)
{
  __shared__ float wsum[16][4];
  __shared__ float st[4];
  const int t = threadIdx.x;
  float s0 = 0.f, q0 = 0.f, s1 = 0.f, q1 = 0.f;
  for (int r = t; r < B_N; r += 1024) {
    float v0 = y[2*r], v1 = y[2*r + 1];
    s0 += v0; q0 += v0 * v0;
    s1 += v1; q1 += v1 * v1;
  }
  #pragma unroll
  for (int off = 32; off >= 1; off >>= 1) {
    s0 += __shfl_down(s0, off); q0 += __shfl_down(q0, off);
    s1 += __shfl_down(s1, off); q1 += __shfl_down(q1, off);
  }
  if ((t & 63) == 0) { int w = t >> 6; wsum[w][0]=s0; wsum[w][1]=q0; wsum[w][2]=s1; wsum[w][3]=q1; }
  __syncthreads();
  if (t == 0) {
    float S0=0.f,Q0=0.f,S1=0.f,Q1=0.f;
    for (int w = 0; w < 16; ++w) { S0+=wsum[w][0]; Q0+=wsum[w][1]; S1+=wsum[w][2]; Q1+=wsum[w][3]; }
    float n = (float)B_N;
    float mu0 = S0 / n, var0 = Q0 / n - mu0 * mu0;
    float mu1 = S1 / n, var1 = Q1 / n - mu1 * mu1;
    st[0] = mu0; st[1] = rsqrtf(var0 + EPS_F);
    st[2] = mu1; st[3] = rsqrtf(var1 + EPS_F);
  }
  __syncthreads();
  float g0 = g_out[0], g1 = g_out[1], bo0 = b_out[0], bo1 = b_out[1];
  float mu0 = st[0], rs0 = st[1], mu1 = st[2], rs1 = st[3];
  for (int r = t; r < B_N; r += 1024) {
    out[2*r]     = (y[2*r]     - mu0) * rs0 * g0 + bo0;
    out[2*r + 1] = (y[2*r + 1] - mu1) * rs1 * g1 + bo1;
  }
}

extern "C" void kernel_launch(void* const* d_in, const int* in_sizes, int n_in,
                              void* d_out, int out_size, void* d_ws, size_t ws_size,
                              hipStream_t stream) {
  (void)in_sizes; (void)n_in; (void)out_size; (void)ws_size;
  const float* x    = (const float*)d_in[0];
  // d_in[1] = h_0 (unused by the reference)
  const float* Wr   = (const float*)d_in[2];
  const float* Wi   = (const float*)d_in[3];
  const float* Wfr  = (const float*)d_in[4];
  const float* Wfi  = (const float*)d_in[5];
  const float* g_in = (const float*)d_in[6];
  const float* b_in = (const float*)d_in[7];
  const float* g_out= (const float*)d_in[8];
  const float* b_out= (const float*)d_in[9];
  float* out = (float*)d_out;

  char* ws = (char*)d_ws;
  float* AC    = (float*)(ws + 128);          // 32 f: A[16], C[16]
  float* RWr   = (float*)(ws + 256);          // 2048 f
  float* RWi   = (float*)(ws + 256 + 8192);
  float* Kr    = (float*)(ws + 256 + 16384);
  float* Ki    = (float*)(ws + 256 + 24576);
  float* y     = (float*)(ws + 33024);        // 32768 f (B x 2)
  // partials overlaps wr_bf: finalize consumes it BEFORE wprep writes wr_bf (same stream order)
  float* partials = (float*)(ws + 164096);    // 2048*32 f = 256 KB
  unsigned short* wr_bf = (unsigned short*)(ws + 164096);             // 1 MB
  unsigned short* wi_bf = (unsigned short*)(ws + 164096 + 1048576);   // 1 MB
  unsigned short* xplan = (unsigned short*)(ws + 2261248);            // 128 MB: 16 planes of P_N bf16

  pass1_kernel<<<2048, 256, 0, stream>>>(x, xplan, partials);
  finalize_kernel<<<1, 1024, 0, stream>>>(partials, g_in, b_in, AC);
  wprep_kernel<<<2048, 256, 0, stream>>>(Wr, Wi, wr_bf, wi_bf, RWr, RWi);
  kterm_kernel<<<8, 256, 0, stream>>>(AC, RWr, RWi, Kr, Ki);
  main_kernel<<<B_N / 32, 256, 0, stream>>>(xplan, wr_bf, wi_bf, AC, Kr, Ki, Wfr, Wfi, y);
  ln_kernel<<<1, 1024, 0, stream>>>(y, g_out, b_out, out);
}

// Round 4
// 201.812 us; speedup vs baseline: 5.1463x; 1.0253x over previous
//
#include <hip/hip_runtime.h>
#include <stdint.h>

#define B_N   16384
#define S_N   256
#define NCH   8
#define P_N   (B_N * S_N)      // 4194304 positions (b,s)
#define EPS_F 1e-5f

typedef float  f32x4  __attribute__((ext_vector_type(4)));
typedef __bf16 bf16x8 __attribute__((ext_vector_type(8)));
typedef unsigned int u32x4 __attribute__((ext_vector_type(4)));
typedef unsigned int u32x2 __attribute__((ext_vector_type(2)));

static __device__ __forceinline__ unsigned short f2bf(float f) {
  union { float f; unsigned u; } v; v.f = f;
  unsigned u = v.u;
  u += 0x7fffu + ((u >> 16) & 1u);          // RNE
  return (unsigned short)(u >> 16);
}
static __device__ __forceinline__ float bf2f(unsigned short h) {
  union { unsigned u; float f; } v; v.u = ((unsigned)h) << 16;
  return v.f;
}

typedef const __attribute__((address_space(1))) unsigned int* gas1_t;
typedef __attribute__((address_space(3))) unsigned int* las3_t;
// async global->LDS, 16B per lane; LDS dest must be linear (base + lane*16)
static __device__ __forceinline__ void gl16(const void* g, void* l) {
  __builtin_amdgcn_global_load_lds((gas1_t)(uintptr_t)g,
                                   (las3_t)(unsigned int)(uintptr_t)l, 16, 0, 0);
}

// ---------------- pass 1: per-channel stats partials + planar bf16 transpose ----------------
__global__ __launch_bounds__(256) void pass1_kernel(
    const float* __restrict__ x, unsigned short* __restrict__ xplan,
    float* __restrict__ partials)
{
  __shared__ float ps[4][32];
  const int t = threadIdx.x;
  const int q = t & 3;               // channel quad: interleaved channels 4q..4q+3
  const int pg = t >> 2;             // 0..63 position-group within tile
  float s[4] = {0.f,0.f,0.f,0.f}, ss[4] = {0.f,0.f,0.f,0.f};
  const f32x4* xv = (const f32x4*)x;

  for (int it = 0; it < 4; ++it) {
    size_t p0 = ((size_t)blockIdx.x * 4 + it) * 512 + (size_t)pg * 8;
    f32x4 v[8];
    #pragma unroll
    for (int j = 0; j < 8; ++j) v[j] = xv[(p0 + j) * 4 + q];
    #pragma unroll
    for (int j = 0; j < 8; ++j)
      #pragma unroll
      for (int k = 0; k < 4; ++k) { s[k] += v[j][k]; ss[k] += v[j][k] * v[j][k]; }
    #pragma unroll
    for (int j2 = 0; j2 < 4; ++j2) {
      u32x4 w;
      #pragma unroll
      for (int k = 0; k < 4; ++k)
        w[k] = (unsigned)f2bf(v[2*k][j2]) | ((unsigned)f2bf(v[2*k+1][j2]) << 16);
      *(u32x4*)(xplan + (size_t)(q * 4 + j2) * P_N + p0) = w;
    }
  }

  #pragma unroll
  for (int off = 32; off >= 4; off >>= 1) {
    #pragma unroll
    for (int k = 0; k < 4; ++k) { s[k] += __shfl_down(s[k], off); ss[k] += __shfl_down(ss[k], off); }
  }
  const int lane = t & 63, wid = t >> 6;
  if (lane < 4) {
    #pragma unroll
    for (int k = 0; k < 4; ++k) {
      ps[wid][lane * 4 + k]      = s[k];
      ps[wid][16 + lane * 4 + k] = ss[k];
    }
  }
  __syncthreads();
  if (t < 32)
    partials[blockIdx.x * 32 + t] = ps[0][t] + ps[1][t] + ps[2][t] + ps[3][t];
}

// ---------------- finalize: reduce partials -> A,C ----------------
__global__ __launch_bounds__(1024) void finalize_kernel(
    const float* __restrict__ partials, const float* __restrict__ g_in,
    const float* __restrict__ b_in, float* __restrict__ AC)
{
  __shared__ float acc[32][32];
  const int t = threadIdx.x;
  const int v = t & 31, chunk = t >> 5;
  float s = 0.f;
  for (int i = 0; i < 64; ++i)
    s += partials[(size_t)(chunk * 64 + i) * 32 + v];
  acc[chunk][v] = s;
  __syncthreads();
  if (t < 32) {
    float tot = 0.f;
    #pragma unroll
    for (int k = 0; k < 32; ++k) tot += acc[k][t];
    acc[0][t] = tot;
  }
  __syncthreads();
  if (t < 16) {
    float n = (float)P_N;
    float mu  = acc[0][t] / n;
    float var = acc[0][16 + t] / n - mu * mu;
    float A = g_in[t] * rsqrtf(var + EPS_F);
    AC[t] = A;
    AC[16 + t] = b_in[t] - mu * A;
  }
}

// ---------------- W prep: fp32 -> bf16 + rowsums ----------------
__global__ __launch_bounds__(256) void wprep_kernel(
    const float* __restrict__ Wr, const float* __restrict__ Wi,
    unsigned short* __restrict__ wr_bf, unsigned short* __restrict__ wi_bf,
    float* __restrict__ RWr, float* __restrict__ RWi)
{
  __shared__ float sr[4], si[4];
  const int row = blockIdx.x, t = threadIdx.x;   // row = c*256 + o
  const size_t idx = (size_t)row * 256 + t;
  float vr = Wr[idx], vi = Wi[idx];
  wr_bf[idx] = f2bf(vr);
  wi_bf[idx] = f2bf(vi);
  float rr = vr, ri = vi;
  #pragma unroll
  for (int off = 32; off >= 1; off >>= 1) { rr += __shfl_down(rr, off); ri += __shfl_down(ri, off); }
  if ((t & 63) == 0) { sr[t >> 6] = rr; si[t >> 6] = ri; }
  __syncthreads();
  if (t == 0) {
    RWr[row] = sr[0] + sr[1] + sr[2] + sr[3];
    RWi[row] = si[0] + si[1] + si[2] + si[3];
  }
}

// ---------------- K terms ----------------
__global__ __launch_bounds__(256) void kterm_kernel(
    const float* __restrict__ AC, const float* __restrict__ RWr, const float* __restrict__ RWi,
    float* __restrict__ Kr, float* __restrict__ Ki)
{
  int idx = blockIdx.x * 256 + threadIdx.x;   // 2048 = c*256+o
  int c = idx >> 8;
  float Ci_ = AC[16 + 2*c], Cq_ = AC[16 + 2*c + 1];
  Kr[idx] = Ci_ * RWr[idx] - Cq_ * RWi[idx];
  Ki[idx] = Cq_ * RWr[idx] + Ci_ * RWi[idx];
}

// W chunk stage: 16KB = 128 o-rows x 128B (Wr|Wi 16B-granules interleaved, XOR-swizzled)
static __device__ __forceinline__ void issue_w(
    const unsigned short* __restrict__ wr_bf, const unsigned short* __restrict__ wi_bf,
    int c, int u, char* wbuf, int t)
{
  const int oh = u >> 3, c32 = u & 7;
  #pragma unroll
  for (int i = 0; i < 4; ++i) {
    const int L = i * 4096 + t * 16;            // linear LDS byte (lane*16 within wave)
    const int row = i * 32 + (t >> 3);          // o-row 0..127
    const int ds_ = (t & 7) ^ (row & 7);        // data granule: plane = ds_>>2, kslot = ds_&3
    const unsigned short* wb = (ds_ & 4) ? wi_bf : wr_bf;
    const char* g = (const char*)(wb + (size_t)(c * 256 + oh * 128 + row) * 256
                                     + c32 * 32 + (ds_ & 3) * 8);
    gl16(g, wbuf + L);
  }
}

static __device__ __forceinline__ void issue_x(
    const unsigned short* __restrict__ xplan, int c, int b0, char* xlds, int t)
{
  #pragma unroll
  for (int i = 0; i < 8; ++i) {
    const int plane = i >> 2, si = i & 3;
    const int L = plane * 16384 + si * 4096 + t * 16;
    const int row = si * 8 + (t >> 5);              // batch row 0..31
    const int gd = (t & 31) ^ (row & 7);            // data granule at this slot
    const char* g = (const char*)xplan
        + (((size_t)(2 * c + plane) * P_N + (size_t)(b0 + row) * 256) << 1) + (gd << 4);
    gl16(g, xlds + L);
  }
}

// ---------------- main: complex MFMA matmul + amp2-weighted contraction ----------------
// 512 blocks x 256 thr; 32 batch rows/block; W triple-buffered k=32 chunks,
// depth-2 pipeline: counted vmcnt(4) + raw s_barrier (loads stay in flight across barrier).
__global__ __launch_bounds__(256, 2) void main_kernel(
    const unsigned short* __restrict__ xplan,
    const unsigned short* __restrict__ wr_bf,
    const unsigned short* __restrict__ wi_bf,
    const float* __restrict__ AC,
    const float* __restrict__ Kr, const float* __restrict__ Ki,
    const float* __restrict__ Wfr, const float* __restrict__ Wfi,
    float* __restrict__ y)
{
  __shared__ char Xlds[32768];     // 2 planes x 32 rows x 512B, 16B-granule XOR swizzle (row&7)
  __shared__ char Wlds[49152];     // 3 bufs x 16 KB  (total LDS = exactly 80 KB -> 2 blocks/CU)
  float (*red)[32][2] = (float(*)[32][2])Wlds;   // aliased after final sync

  const int t = threadIdx.x;
  const int wid = t >> 6, lane = t & 63;
  const int col = lane & 15, kg = lane >> 4;
  const int b0 = blockIdx.x * 32;

  float pCr[2][4], pCi[2][4];
  #pragma unroll
  for (int m = 0; m < 2; ++m)
    #pragma unroll
    for (int r = 0; r < 4; ++r) { pCr[m][r] = 0.f; pCi[m][r] = 0.f; }

  for (int c = 0; c < NCH; ++c) {
    // all waves past previous channel's epilogue reads of Xlds; pipeline fully drained
    __builtin_amdgcn_s_barrier();
    issue_x(xplan, c, b0, Xlds, t);                 // 8 loads
    issue_w(wr_bf, wi_bf, c, 0, Wlds, t);           // 4 loads -> buf 0
    int wsel = 0;

    for (int oh = 0; oh < 2; ++oh) {
      f32x4 Srr[2][2], Sqi[2][2], Sqr[2][2], Sii[2][2];
      #pragma unroll
      for (int m = 0; m < 2; ++m)
        #pragma unroll
        for (int n = 0; n < 2; ++n) {
          Srr[m][n] = (f32x4){0.f,0.f,0.f,0.f};
          Sqi[m][n] = (f32x4){0.f,0.f,0.f,0.f};
          Sqr[m][n] = (f32x4){0.f,0.f,0.f,0.f};
          Sii[m][n] = (f32x4){0.f,0.f,0.f,0.f};
        }
      #pragma unroll
      for (int t7 = 0; t7 < 8; ++t7) {
        const int u = oh * 8 + t7;
        const int nsel = (wsel == 2) ? 0 : wsel + 1;
        if (u < 15) {
          issue_w(wr_bf, wi_bf, c, u + 1, Wlds + nsel * 16384, t);  // prefetch, stays in flight
          asm volatile("s_waitcnt vmcnt(4)" ::: "memory");          // chunk u (and X at u=0) done
        } else {
          asm volatile("s_waitcnt vmcnt(0)" ::: "memory");          // channel-boundary drain
        }
        __builtin_amdgcn_s_barrier();              // raw: no vmcnt(0) drain of the prefetch
        __builtin_amdgcn_sched_barrier(0);

        // A frags: rows col / 16+col (same &7), k-granule = t7*4 + kg
        const int axo = (((t7 * 4 + kg) ^ (col & 7)) << 4);
        bf16x8 ari0 = *(const bf16x8*)(Xlds + col * 512 + axo);
        bf16x8 ari1 = *(const bf16x8*)(Xlds + (16 + col) * 512 + axo);
        bf16x8 aqi0 = *(const bf16x8*)(Xlds + 16384 + col * 512 + axo);
        bf16x8 aqi1 = *(const bf16x8*)(Xlds + 16384 + (16 + col) * 512 + axo);
        const char* Wb = Wlds + wsel * 16384;
        #pragma unroll
        for (int nf = 0; nf < 2; ++nf) {
          const int r = wid * 32 + nf * 16 + col;
          bf16x8 br = *(const bf16x8*)(Wb + r * 128 + (((kg    ) ^ (r & 7)) << 4));
          bf16x8 bi = *(const bf16x8*)(Wb + r * 128 + (((kg + 4) ^ (r & 7)) << 4));
          Srr[0][nf] = __builtin_amdgcn_mfma_f32_16x16x32_bf16(ari0, br, Srr[0][nf], 0,0,0);
          Srr[1][nf] = __builtin_amdgcn_mfma_f32_16x16x32_bf16(ari1, br, Srr[1][nf], 0,0,0);
          Sqr[0][nf] = __builtin_amdgcn_mfma_f32_16x16x32_bf16(aqi0, br, Sqr[0][nf], 0,0,0);
          Sqr[1][nf] = __builtin_amdgcn_mfma_f32_16x16x32_bf16(aqi1, br, Sqr[1][nf], 0,0,0);
          Sii[0][nf] = __builtin_amdgcn_mfma_f32_16x16x32_bf16(ari0, bi, Sii[0][nf], 0,0,0);
          Sii[1][nf] = __builtin_amdgcn_mfma_f32_16x16x32_bf16(ari1, bi, Sii[1][nf], 0,0,0);
          Sqi[0][nf] = __builtin_amdgcn_mfma_f32_16x16x32_bf16(aqi0, bi, Sqi[0][nf], 0,0,0);
          Sqi[1][nf] = __builtin_amdgcn_mfma_f32_16x16x32_bf16(aqi1, bi, Sqi[1][nf], 0,0,0);
        }
        __builtin_amdgcn_sched_barrier(0);
        wsel = nsel;
      }

      // epilogue: fold affine + K terms, amp2 weighting, accumulate per-b
      const float Ai_ = AC[2*c],      Aq_ = AC[2*c + 1];
      const float Cin = AC[16 + 2*c], Cqn = AC[16 + 2*c + 1];
      #pragma unroll
      for (int nf = 0; nf < 2; ++nf) {
        const int o = oh * 128 + wid * 32 + nf * 16 + col;
        const int gidx = c * 256 + o;
        const float kr = Kr[gidx], ki = Ki[gidx];
        const float wfr = Wfr[gidx], wfi = Wfi[gidx];
        const int og = o >> 3, ob = (o & 7) * 2;
        #pragma unroll
        for (int mf = 0; mf < 2; ++mf) {
          const int bl = mf * 16 + kg * 4;
          #pragma unroll
          for (int r = 0; r < 4; ++r) {
            const int row = bl + r;
            const int sb = row * 512 + ((og ^ (row & 7)) << 4) + ob;
            float xiv = Ai_ * bf2f(*(const unsigned short*)(Xlds + sb)) + Cin;
            float xqv = Aq_ * bf2f(*(const unsigned short*)(Xlds + 16384 + sb)) + Cqn;
            float cr = Ai_ * Srr[mf][nf][r] - Aq_ * Sqi[mf][nf][r] + kr;
            float ci = Aq_ * Sqr[mf][nf][r] + Ai_ * Sii[mf][nf][r] + ki;
            float amp2 = xiv * xiv + xqv * xqv;
            pCr[mf][r] += amp2 * (cr * wfr - ci * wfi);
            pCi[mf][r] += amp2 * (ci * wfr + cr * wfi);
          }
        }
      }
    }
  }

  // sum over the 16 o-columns within each lane group
  #pragma unroll
  for (int off = 1; off < 16; off <<= 1) {
    #pragma unroll
    for (int m = 0; m < 2; ++m)
      #pragma unroll
      for (int r = 0; r < 4; ++r) {
        pCr[m][r] += __shfl_xor(pCr[m][r], off);
        pCi[m][r] += __shfl_xor(pCi[m][r], off);
      }
  }
  __syncthreads();   // full drain: safe to reuse Wlds space as `red`
  if (col == 0) {
    #pragma unroll
    for (int m = 0; m < 2; ++m)
      #pragma unroll
      for (int r = 0; r < 4; ++r) {
        red[wid][m*16 + kg*4 + r][0] = pCr[m][r];
        red[wid][m*16 + kg*4 + r][1] = pCi[m][r];
      }
  }
  __syncthreads();
  if (t < 64) {
    int bl = t >> 1, cc = t & 1;
    float v = red[0][bl][cc] + red[1][bl][cc] + red[2][bl][cc] + red[3][bl][cc];
    y[(size_t)(b0 + bl) * 2 + cc] = v;
  }
}

// ---------------- final batch LayerNorm over y (B,2) ----------------
__global__ __launch_bounds__(1024) void ln_kernel(
    const float* __restrict__ y, const float* __restrict__ g_out, const float* __restrict__ b_out,
    float* __restrict__ out)
{
  __shared__ float wsum[16][4];
  __shared__ float st[4];
  const int t = threadIdx.x;
  float s0 = 0.f, q0 = 0.f, s1 = 0.f, q1 = 0.f;
  for (int r = t; r < B_N; r += 1024) {
    float v0 = y[2*r], v1 = y[2*r + 1];
    s0 += v0; q0 += v0 * v0;
    s1 += v1; q1 += v1 * v1;
  }
  #pragma unroll
  for (int off = 32; off >= 1; off >>= 1) {
    s0 += __shfl_down(s0, off); q0 += __shfl_down(q0, off);
    s1 += __shfl_down(s1, off); q1 += __shfl_down(q1, off);
  }
  if ((t & 63) == 0) { int w = t >> 6; wsum[w][0]=s0; wsum[w][1]=q0; wsum[w][2]=s1; wsum[w][3]=q1; }
  __syncthreads();
  if (t == 0) {
    float S0=0.f,Q0=0.f,S1=0.f,Q1=0.f;
    for (int w = 0; w < 16; ++w) { S0+=wsum[w][0]; Q0+=wsum[w][1]; S1+=wsum[w][2]; Q1+=wsum[w][3]; }
    float n = (float)B_N;
    float mu0 = S0 / n, var0 = Q0 / n - mu0 * mu0;
    float mu1 = S1 / n, var1 = Q1 / n - mu1 * mu1;
    st[0] = mu0; st[1] = rsqrtf(var0 + EPS_F);
    st[2] = mu1; st[3] = rsqrtf(var1 + EPS_F);
  }
  __syncthreads();
  float g0 = g_out[0], g1 = g_out[1], bo0 = b_out[0], bo1 = b_out[1];
  float mu0 = st[0], rs0 = st[1], mu1 = st[2], rs1 = st[3];
  for (int r = t; r < B_N; r += 1024) {
    out[2*r]     = (y[2*r]     - mu0) * rs0 * g0 + bo0;
    out[2*r + 1] = (y[2*r + 1] - mu1) * rs1 * g1 + bo1;
  }
}

extern "C" void kernel_launch(void* const* d_in, const int* in_sizes, int n_in,
                              void* d_out, int out_size, void* d_ws, size_t ws_size,
                              hipStream_t stream) {
  (void)in_sizes; (void)n_in; (void)out_size; (void)ws_size;
  const float* x    = (const float*)d_in[0];
  // d_in[1] = h_0 (unused by the reference)
  const float* Wr   = (const float*)d_in[2];
  const float* Wi   = (const float*)d_in[3];
  const float* Wfr  = (const float*)d_in[4];
  const float* Wfi  = (const float*)d_in[5];
  const float* g_in = (const float*)d_in[6];
  const float* b_in = (const float*)d_in[7];
  const float* g_out= (const float*)d_in[8];
  const float* b_out= (const float*)d_in[9];
  float* out = (float*)d_out;

  char* ws = (char*)d_ws;
  float* AC    = (float*)(ws + 128);          // 32 f: A[16], C[16]
  float* RWr   = (float*)(ws + 256);          // 2048 f
  float* RWi   = (float*)(ws + 256 + 8192);
  float* Kr    = (float*)(ws + 256 + 16384);
  float* Ki    = (float*)(ws + 256 + 24576);
  float* y     = (float*)(ws + 33024);        // 32768 f (B x 2)
  // partials overlaps wr_bf: finalize consumes it BEFORE wprep writes wr_bf (same stream order)
  float* partials = (float*)(ws + 164096);    // 2048*32 f = 256 KB
  unsigned short* wr_bf = (unsigned short*)(ws + 164096);             // 1 MB
  unsigned short* wi_bf = (unsigned short*)(ws + 164096 + 1048576);   // 1 MB
  unsigned short* xplan = (unsigned short*)(ws + 2261248);            // 128 MB: 16 planes of P_N bf16

  pass1_kernel<<<2048, 256, 0, stream>>>(x, xplan, partials);
  finalize_kernel<<<1, 1024, 0, stream>>>(partials, g_in, b_in, AC);
  wprep_kernel<<<2048, 256, 0, stream>>>(Wr, Wi, wr_bf, wi_bf, RWr, RWi);
  kterm_kernel<<<8, 256, 0, stream>>>(AC, RWr, RWi, Kr, Ki);
  main_kernel<<<B_N / 32, 256, 0, stream>>>(xplan, wr_bf, wi_bf, AC, Kr, Ki, Wfr, Wfi, y);
  ln_kernel<<<1, 1024, 0, stream>>>(y, g_out, b_out, out);
}